// Round 2
// baseline (44525.296 us; speedup 1.0000x reference)
//
#include <hip/hip_runtime.h>
#include <math.h>

#define PI2 6.2831853071795864769f

// ---------------------------------------------------------------- sentinel (ws too small diagnostic)
__global__ void sentinel_kernel(float* __restrict__ out, int n) {
    int t = blockIdx.x * 256 + threadIdx.x;
    if (t < n) out[t] = 12345.0f;
}

// ---------------------------------------------------------------- encoder
// h[b,c,p] = (enc_w[c,0]*x[b,0,p] + enc_w[c,1]*x[b,1,p] + enc_b[c])*8 + pos[c,p]
__global__ void enc_kernel(const float* __restrict__ x, const float* __restrict__ w,
                           const float* __restrict__ b, const float* __restrict__ pos,
                           float* __restrict__ h) {
    long t = (long)blockIdx.x * 256 + threadIdx.x;   // 0 .. 4*128*65536-1
    int p  = (int)(t & 65535);
    int c  = (int)((t >> 16) & 127);
    int bb = (int)(t >> 23);
    float x0 = x[((long)bb * 2 + 0) * 65536 + p];
    float x1 = x[((long)bb * 2 + 1) * 65536 + p];
    float v  = (w[c * 2] * x0 + w[c * 2 + 1] * x1 + b[c]) * 8.0f + pos[(long)c * 65536 + p];
    h[t] = v;
}

// ---------------------------------------------------------------- W2 transpose
// w2t[hd,o] = w2[o,hd]   (w2: 128 x 512)
__global__ void transpose_w2(const float* __restrict__ w2, float* __restrict__ w2t) {
    int t = blockIdx.x * 256 + threadIdx.x;   // 0..65535
    int o = t >> 9, hd = t & 511;
    w2t[hd * 128 + o] = w2[t];                // t == o*512+hd
}

// ---------------------------------------------------------------- fused MLP (one batch)
// out[o,p] = conv2( silu( conv1(h_b) ) )   per-pixel, weights via scalar loads
__global__ __launch_bounds__(256, 1)
void mlp_kernel(const float* __restrict__ h, const float* __restrict__ w1,
                const float* __restrict__ b1, const float* __restrict__ w2t,
                const float* __restrict__ b2, float* __restrict__ out) {
    int p = blockIdx.x * 256 + threadIdx.x;   // 0..65535
    const float* hb = h + p;
    float x[128];
#pragma unroll
    for (int c = 0; c < 128; c++) x[c] = hb[(long)c * 65536];
    float acc[128];
#pragma unroll
    for (int o = 0; o < 128; o++) acc[o] = b2[o];

#pragma unroll 2
    for (int hd = 0; hd < 512; hd++) {
        const float* wr = w1 + hd * 128;
        float s0 = 0.f, s1 = 0.f, s2 = 0.f, s3 = 0.f;
#pragma unroll
        for (int c = 0; c < 128; c += 4) {
            s0 += wr[c + 0] * x[c + 0];
            s1 += wr[c + 1] * x[c + 1];
            s2 += wr[c + 2] * x[c + 2];
            s3 += wr[c + 3] * x[c + 3];
        }
        float pre = (s0 + s1) + (s2 + s3) + b1[hd];
        float sig = 1.0f / (1.0f + __expf(-pre));
        float hv  = pre * sig;                      // SiLU
        const float* w2r = w2t + hd * 128;
#pragma unroll
        for (int o = 0; o < 128; o++) acc[o] += w2r[o] * hv;
    }
#pragma unroll
    for (int o = 0; o < 128; o++) out[(long)o * 65536 + p] = acc[o];
}

// ---------------------------------------------------------------- row forward rfft (one batch)
// in: real rows of 256 (128 imgs x 256 rows), out: bins 0..128 per row. Unnormalized Stockham.
__global__ void fft_row_fwd(const float* __restrict__ in, float2* __restrict__ freq) {
    __shared__ float2 A[4][256];
    __shared__ float2 B[4][256];
    int tid = threadIdx.x;
    long rowbase = (long)blockIdx.x * 4;          // rows 0..32767
    {
        int r = tid >> 6, l = tid & 63;
        const float4* src = (const float4*)(in + (rowbase + r) * 256);
        float4 v = src[l];
        A[r][l * 4 + 0] = make_float2(v.x, 0.f);
        A[r][l * 4 + 1] = make_float2(v.y, 0.f);
        A[r][l * 4 + 2] = make_float2(v.z, 0.f);
        A[r][l * 4 + 3] = make_float2(v.w, 0.f);
    }
    __syncthreads();
    float2 (*s)[256] = A; float2 (*d)[256] = B;
    for (int m = 1; m < 256; m <<= 1) {
#pragma unroll
        for (int q = 0; q < 2; q++) {
            int bf = tid + q * 256;               // 0..511
            int r = bf >> 7, i = bf & 127;
            int jm = i & ~(m - 1);
            float2 c0 = s[r][i], c1 = s[r][i + 128];
            float ang = -(PI2 / 256.f) * (float)jm;
            float sn, cs; __sincosf(ang, &sn, &cs);
            float2 df = make_float2(c0.x - c1.x, c0.y - c1.y);
            d[r][i + jm]     = make_float2(c0.x + c1.x, c0.y + c1.y);
            d[r][i + jm + m] = make_float2(cs * df.x - sn * df.y, cs * df.y + sn * df.x);
        }
        __syncthreads();
        float2 (*tmp)[256] = s; s = d; d = tmp;
    }
    for (int q = tid; q < 4 * 129; q += 256) {
        int r = q / 129; int k = q - r * 129;
        freq[(rowbase + r) * 129 + k] = s[r][k];
    }
}

// ---------------------------------------------------------------- column FFT + filter + inverse column FFT (one batch)
// freq layout: [c][y][kx], c = 0..127.  8 columns per block, in place.
__global__ void fft_col(float2* __restrict__ freq, const float* __restrict__ mags,
                        const float* __restrict__ phases) {
    __shared__ float2 A[8][256];
    __shared__ float2 B[8][256];
    int tid = threadIdx.x;
    int img = blockIdx.x / 17;                    // channel 0..127
    int kt  = blockIdx.x % 17;
    int kx0 = kt * 8;
    long base = (long)img * 256 * 129;
#pragma unroll
    for (int q = 0; q < 8; q++) {
        int e = tid + q * 256;
        int cl = e & 7, y = e >> 3;
        int kx = kx0 + cl;
        if (kx < 129) A[cl][y] = freq[base + (long)y * 129 + kx];
    }
    __syncthreads();
    float2 (*s)[256] = A; float2 (*d)[256] = B;
    for (int m = 1; m < 256; m <<= 1) {           // forward stages (sign -1)
#pragma unroll
        for (int q = 0; q < 4; q++) {
            int bf = tid + q * 256;               // 0..1023
            int cl = bf >> 7, i = bf & 127;
            int jm = i & ~(m - 1);
            float2 c0 = s[cl][i], c1 = s[cl][i + 128];
            float ang = -(PI2 / 256.f) * (float)jm;
            float sn, cs; __sincosf(ang, &sn, &cs);
            float2 df = make_float2(c0.x - c1.x, c0.y - c1.y);
            d[cl][i + jm]     = make_float2(c0.x + c1.x, c0.y + c1.y);
            d[cl][i + jm + m] = make_float2(cs * df.x - sn * df.y, cs * df.y + sn * df.x);
        }
        __syncthreads();
        float2 (*tmp)[256] = s; s = d; d = tmp;
    }
    // filter: xf = mask ? xf * sigmoid(mag)*exp(i*phase) : 0
#pragma unroll
    for (int q = 0; q < 8; q++) {
        int e = tid + q * 256;
        int cl = e & 7, ky = e >> 3;
        int kx = kx0 + cl;
        float2 v = s[cl][ky];
        float2 r = make_float2(0.f, 0.f);
        if (kx < 129) {
            int ry = ky < 128 ? ky : ky - 256;
            if (kx * kx + ry * ry <= 16384) {
                long fi = ((long)img * 256 + ky) * 129 + kx;
                float mg = mags[fi], ph = phases[fi];
                float sg = 1.0f / (1.0f + __expf(-mg));
                float sn, cs; __sincosf(ph, &sn, &cs);
                float fr = sg * cs, fim = sg * sn;
                r = make_float2(v.x * fr - v.y * fim, v.x * fim + v.y * fr);
            }
        }
        s[cl][ky] = r;
    }
    __syncthreads();
    for (int m = 1; m < 256; m <<= 1) {           // inverse stages (sign +1)
#pragma unroll
        for (int q = 0; q < 4; q++) {
            int bf = tid + q * 256;
            int cl = bf >> 7, i = bf & 127;
            int jm = i & ~(m - 1);
            float2 c0 = s[cl][i], c1 = s[cl][i + 128];
            float ang = (PI2 / 256.f) * (float)jm;
            float sn, cs; __sincosf(ang, &sn, &cs);
            float2 df = make_float2(c0.x - c1.x, c0.y - c1.y);
            d[cl][i + jm]     = make_float2(c0.x + c1.x, c0.y + c1.y);
            d[cl][i + jm + m] = make_float2(cs * df.x - sn * df.y, cs * df.y + sn * df.x);
        }
        __syncthreads();
        float2 (*tmp)[256] = s; s = d; d = tmp;
    }
#pragma unroll
    for (int q = 0; q < 8; q++) {
        int e = tid + q * 256;
        int cl = e & 7, y = e >> 3;
        int kx = kx0 + cl;
        if (kx < 129) freq[base + (long)y * 129 + kx] = s[cl][y];
    }
}

// ---------------------------------------------------------------- row inverse rfft (one batch)
// Hermitian-extend bins 0..128, inverse FFT, keep real, scale by 1/65536.
__global__ void fft_row_inv(const float2* __restrict__ freq, float* __restrict__ out) {
    __shared__ float2 A[4][256];
    __shared__ float2 B[4][256];
    int tid = threadIdx.x;
    long rowbase = (long)blockIdx.x * 4;
#pragma unroll
    for (int q = 0; q < 4; q++) {
        int e = tid + q * 256;                    // 0..1023
        int r = e >> 8, xx = e & 255;
        const float2* fr = freq + (rowbase + r) * 129;
        float2 v;
        if (xx <= 128) v = fr[xx];
        else { float2 w = fr[256 - xx]; v = make_float2(w.x, -w.y); }
        A[r][xx] = v;
    }
    __syncthreads();
    float2 (*s)[256] = A; float2 (*d)[256] = B;
    for (int m = 1; m < 256; m <<= 1) {
#pragma unroll
        for (int q = 0; q < 2; q++) {
            int bf = tid + q * 256;
            int r = bf >> 7, i = bf & 127;
            int jm = i & ~(m - 1);
            float2 c0 = s[r][i], c1 = s[r][i + 128];
            float ang = (PI2 / 256.f) * (float)jm;
            float sn, cs; __sincosf(ang, &sn, &cs);
            float2 df = make_float2(c0.x - c1.x, c0.y - c1.y);
            d[r][i + jm]     = make_float2(c0.x + c1.x, c0.y + c1.y);
            d[r][i + jm + m] = make_float2(cs * df.x - sn * df.y, cs * df.y + sn * df.x);
        }
        __syncthreads();
        float2 (*tmp)[256] = s; s = d; d = tmp;
    }
    {
        int r = tid >> 6, l = tid & 63;
        float4* dst = (float4*)(out + (rowbase + r) * 256);
        const float sc = 1.0f / 65536.0f;
        float4 v;
        v.x = s[r][l * 4 + 0].x * sc;
        v.y = s[r][l * 4 + 1].x * sc;
        v.z = s[r][l * 4 + 2].x * sc;
        v.w = s[r][l * 4 + 3].x * sc;
        dst[l] = v;
    }
}

// ---------------------------------------------------------------- oxo conv + residual (one batch)
// h[o,p] += sum_c oxo_w[o,c]*t2[c,p] + oxo_b[o]
__global__ void oxo_kernel(const float* __restrict__ t2, const float* __restrict__ w,
                           const float* __restrict__ b, float* __restrict__ h) {
    int p = blockIdx.x * 256 + threadIdx.x;       // 0..65535
    float x[128];
#pragma unroll
    for (int c = 0; c < 128; c++) x[c] = t2[(long)c * 65536 + p];
#pragma unroll 1
    for (int o = 0; o < 128; o++) {
        const float* wr = w + o * 128;
        float s0 = 0.f, s1 = 0.f, s2 = 0.f, s3 = 0.f;
#pragma unroll
        for (int c = 0; c < 128; c += 4) {
            s0 += wr[c + 0] * x[c + 0];
            s1 += wr[c + 1] * x[c + 1];
            s2 += wr[c + 2] * x[c + 2];
            s3 += wr[c + 3] * x[c + 3];
        }
        float acc = (s0 + s1) + (s2 + s3) + b[o];
        h[(long)o * 65536 + p] += acc;
    }
}

// ---------------------------------------------------------------- decoder (all batches)
__global__ void dec_kernel(const float* __restrict__ h, const float* __restrict__ w,
                           const float* __restrict__ b, float* __restrict__ out) {
    int t = blockIdx.x * 256 + threadIdx.x;       // 0..262143
    int bb = t >> 16, p = t & 65535;
    const float* hb = h + (long)bb * 128 * 65536 + p;
    float a0 = b[0], a1 = b[1];
    float a0b = 0.f, a1b = 0.f;
#pragma unroll 4
    for (int c = 0; c < 128; c += 2) {
        float h0 = hb[(long)c * 65536];
        float h1 = hb[(long)(c + 1) * 65536];
        a0  += w[c] * h0;        a1  += w[128 + c] * h0;
        a0b += w[c + 1] * h1;    a1b += w[128 + c + 1] * h1;
    }
    out[((long)bb * 2 + 0) * 65536 + p] = (a0 + a0b) * 0.125f;
    out[((long)bb * 2 + 1) * 65536 + p] = (a1 + a1b) * 0.125f;
}

// ---------------------------------------------------------------- launch
extern "C" void kernel_launch(void* const* d_in, const int* in_sizes, int n_in,
                              void* d_out, int out_size, void* d_ws, size_t ws_size,
                              hipStream_t stream) {
    const float* x        = (const float*)d_in[0];
    const float* enc_w    = (const float*)d_in[1];
    const float* enc_b    = (const float*)d_in[2];
    const float* pos_emb  = (const float*)d_in[3];
    const float* mlp_w1   = (const float*)d_in[4];
    const float* mlp_b1   = (const float*)d_in[5];
    const float* mlp_w2   = (const float*)d_in[6];
    const float* mlp_b2   = (const float*)d_in[7];
    const float* spec_mag = (const float*)d_in[8];
    const float* spec_ph  = (const float*)d_in[9];
    const float* oxo_w    = (const float*)d_in[10];
    const float* oxo_b    = (const float*)d_in[11];
    const float* dec_w    = (const float*)d_in[12];
    const float* dec_b    = (const float*)d_in[13];
    float* outp = (float*)d_out;

    // workspace layout (bytes):
    //   h     134,217,728   (4*128*65536 f32, persistent)
    //   t2_b   33,554,432   (128*65536 f32, one batch)
    //   freq_b 33,816,576   (128*256*129 float2, one batch)
    //   w2t       262,144
    // total   201,850,880
    const size_t WS_NEEDED = 201850880ULL;
    if (ws_size < WS_NEEDED) {
        // diagnostic: ws too small -> absmax will read ~12345
        sentinel_kernel<<<(out_size + 255) / 256, 256, 0, stream>>>(outp, out_size);
        return;
    }

    float*  h    = (float*)d_ws;                  // 33,554,432 floats
    float*  t2   = h + 33554432;                  //  8,388,608 floats (one batch)
    float2* freq = (float2*)(t2 + 8388608);       //  4,227,072 float2
    float*  w2t  = (float*)(freq + 4227072);      //     65,536 floats

    enc_kernel<<<131072, 256, 0, stream>>>(x, enc_w, enc_b, pos_emb, h);

    for (int l = 0; l < 4; l++) {
        transpose_w2<<<256, 256, 0, stream>>>(mlp_w2 + (long)l * 65536, w2t);
        const float* w1l = mlp_w1 + (long)l * 65536;
        const float* b1l = mlp_b1 + l * 512;
        const float* b2l = mlp_b2 + l * 128;
        const float* mgl = spec_mag + (long)l * 4227072;
        const float* phl = spec_ph  + (long)l * 4227072;
        const float* owl = oxo_w + (long)l * 16384;
        const float* obl = oxo_b + l * 128;
        for (int b = 0; b < 4; b++) {
            float* hb = h + (long)b * 8388608;
            mlp_kernel<<<256, 256, 0, stream>>>(hb, w1l, b1l, w2t, b2l, t2);
            fft_row_fwd<<<8192, 256, 0, stream>>>(t2, freq);
            fft_col<<<128 * 17, 256, 0, stream>>>(freq, mgl, phl);
            fft_row_inv<<<8192, 256, 0, stream>>>(freq, t2);
            oxo_kernel<<<256, 256, 0, stream>>>(t2, owl, obl, hb);
        }
    }

    dec_kernel<<<1024, 256, 0, stream>>>(h, dec_w, dec_b, outp);
}

// Round 3
// 6548.926 us; speedup vs baseline: 6.7989x; 6.7989x over previous
//
#include <hip/hip_runtime.h>
#include <math.h>

#define PI2 6.2831853071795864769f

typedef short bf16x8 __attribute__((ext_vector_type(8)));
typedef float f32x4 __attribute__((ext_vector_type(4)));
typedef int   i32x4 __attribute__((ext_vector_type(4)));

// ---------------------------------------------------------------- helpers
// split fp32 v into bf16 hi (rne) and bf16 lo (rne of v-hi), packed hi | lo<<16
__device__ inline unsigned splitf(float v) {
    unsigned u  = __float_as_uint(v);
    unsigned r  = (u + 0x7fffu + ((u >> 16) & 1u)) >> 16;
    float hi    = __uint_as_float(r << 16);
    float lof   = v - hi;
    unsigned u2 = __float_as_uint(lof);
    unsigned r2 = (u2 + 0x7fffu + ((u2 >> 16) & 1u)) >> 16;
    return (r & 0xffffu) | (r2 << 16);
}

union VecU { i32x4 i; bf16x8 s; };

// unpack 8 interleaved dwords (as two i32x4) into hi-frag and lo-frag
__device__ inline void unpack2(i32x4 d0, i32x4 d1, bf16x8& hi, bf16x8& lo) {
    VecU h, l;
    h.i.x = __builtin_amdgcn_perm(d0.y, d0.x, 0x05040100);
    h.i.y = __builtin_amdgcn_perm(d0.w, d0.z, 0x05040100);
    h.i.z = __builtin_amdgcn_perm(d1.y, d1.x, 0x05040100);
    h.i.w = __builtin_amdgcn_perm(d1.w, d1.z, 0x05040100);
    l.i.x = __builtin_amdgcn_perm(d0.y, d0.x, 0x07060302);
    l.i.y = __builtin_amdgcn_perm(d0.w, d0.z, 0x07060302);
    l.i.z = __builtin_amdgcn_perm(d1.y, d1.x, 0x07060302);
    l.i.w = __builtin_amdgcn_perm(d1.w, d1.z, 0x07060302);
    hi = h.s; lo = l.s;
}

__device__ inline void unpack8(const int* d, bf16x8& hi, bf16x8& lo) {
    VecU h, l;
    h.i.x = __builtin_amdgcn_perm(d[1], d[0], 0x05040100);
    h.i.y = __builtin_amdgcn_perm(d[3], d[2], 0x05040100);
    h.i.z = __builtin_amdgcn_perm(d[5], d[4], 0x05040100);
    h.i.w = __builtin_amdgcn_perm(d[7], d[6], 0x05040100);
    l.i.x = __builtin_amdgcn_perm(d[1], d[0], 0x07060302);
    l.i.y = __builtin_amdgcn_perm(d[3], d[2], 0x07060302);
    l.i.z = __builtin_amdgcn_perm(d[5], d[4], 0x07060302);
    l.i.w = __builtin_amdgcn_perm(d[7], d[6], 0x07060302);
    hi = h.s; lo = l.s;
}

// ---------------------------------------------------------------- sentinel
__global__ void sentinel_kernel(float* __restrict__ out, int n) {
    int t = blockIdx.x * 256 + threadIdx.x;
    if (t < n) out[t] = 12345.0f;
}

// ---------------------------------------------------------------- split: fp32 -> interleaved bf16 hi/lo dwords
__global__ void split_kernel(const float* __restrict__ in, unsigned* __restrict__ out) {
    long q = (long)blockIdx.x * 256 + threadIdx.x;     // quad index
    const float4* ip = (const float4*)in;
    float4 v = ip[q];
    i32x4 o;
    o.x = (int)splitf(v.x); o.y = (int)splitf(v.y);
    o.z = (int)splitf(v.z); o.w = (int)splitf(v.w);
    ((i32x4*)out)[q] = o;
}

// ---------------------------------------------------------------- encoder (unchanged)
__global__ void enc_kernel(const float* __restrict__ x, const float* __restrict__ w,
                           const float* __restrict__ b, const float* __restrict__ pos,
                           float* __restrict__ h) {
    long t = (long)blockIdx.x * 256 + threadIdx.x;
    int p  = (int)(t & 65535);
    int c  = (int)((t >> 16) & 127);
    int bb = (int)(t >> 23);
    float x0 = x[((long)bb * 2 + 0) * 65536 + p];
    float x1 = x[((long)bb * 2 + 1) * 65536 + p];
    float v  = (w[c * 2] * x0 + w[c * 2 + 1] * x1 + b[c]) * 8.0f + pos[(long)c * 65536 + p];
    h[t] = v;
}

// ---------------------------------------------------------------- GEMM1: hidden = silu(X*W1^T + b1), split-store
// Ax: [128][65536] interleaved dwords (split h, aliases t2 region)
// Bx: W1 [512][128] interleaved dwords.  Sx out: [16384][512] interleaved dwords.
__global__ __launch_bounds__(256, 2)
void gemm1_kernel(const unsigned* __restrict__ Ax, const unsigned* __restrict__ Bx,
                  const float* __restrict__ b1, unsigned* __restrict__ Sx, int p0) {
    int tid = threadIdx.x;
    int w = tid >> 6, l = tid & 63;
    int lr = l & 15, lg = l >> 4;
    int m0 = blockIdx.x * 128;                  // pixel tile within chunk
    int n0 = blockIdx.y * 128 + w * 32;         // hd base for this wave
    f32x4 acc[8][2] = {};
    for (int k0 = 0; k0 < 128; k0 += 32) {
        bf16x8 bh[2], bl[2];
#pragma unroll
        for (int ns = 0; ns < 2; ns++) {
            const unsigned* bp = Bx + (n0 + ns * 16 + lr) * 128 + k0 + lg * 8;
            i32x4 d0 = *(const i32x4*)bp;
            i32x4 d1 = *(const i32x4*)(bp + 4);
            unpack2(d0, d1, bh[ns], bl[ns]);
        }
#pragma unroll
        for (int ms = 0; ms < 8; ms++) {
            const unsigned* ap = Ax + (long)(k0 + lg * 8) * 65536 + p0 + m0 + ms * 16 + lr;
            int d[8];
#pragma unroll
            for (int j = 0; j < 8; j++) d[j] = (int)ap[(long)j * 65536];
            bf16x8 ah, al; unpack8(d, ah, al);
#pragma unroll
            for (int ns = 0; ns < 2; ns++) {
                acc[ms][ns] = __builtin_amdgcn_mfma_f32_16x16x32_bf16(ah, bh[ns], acc[ms][ns], 0, 0, 0);
                acc[ms][ns] = __builtin_amdgcn_mfma_f32_16x16x32_bf16(ah, bl[ns], acc[ms][ns], 0, 0, 0);
                acc[ms][ns] = __builtin_amdgcn_mfma_f32_16x16x32_bf16(al, bh[ns], acc[ms][ns], 0, 0, 0);
            }
        }
    }
#pragma unroll
    for (int ns = 0; ns < 2; ns++) {
        int hd = n0 + ns * 16 + lr;
        float bias = b1[hd];
#pragma unroll
        for (int ms = 0; ms < 8; ms++) {
#pragma unroll
            for (int r = 0; r < 4; r++) {
                float pre = acc[ms][ns][r] + bias;
                float s = pre / (1.0f + __expf(-pre));      // SiLU
                int pix = m0 + ms * 16 + lg * 4 + r;
                Sx[(long)pix * 512 + hd] = splitf(s);
            }
        }
    }
}

// ---------------------------------------------------------------- GEMM2: t2 = hidden*W2^T + b2  (c-major store via LDS)
__global__ __launch_bounds__(256, 2)
void gemm2_kernel(const unsigned* __restrict__ Sx, const unsigned* __restrict__ Bx,
                  const float* __restrict__ b2, float* __restrict__ t2, int p0) {
    __shared__ float T[128 * 128];
    int tid = threadIdx.x;
    int w = tid >> 6, l = tid & 63;
    int lr = l & 15, lg = l >> 4;
    int m0 = blockIdx.x * 128;
    int n0 = w * 32;
    f32x4 acc[8][2] = {};
    for (int k0 = 0; k0 < 512; k0 += 32) {
        bf16x8 bh[2], bl[2];
#pragma unroll
        for (int ns = 0; ns < 2; ns++) {
            const unsigned* bp = Bx + (n0 + ns * 16 + lr) * 512 + k0 + lg * 8;
            i32x4 d0 = *(const i32x4*)bp;
            i32x4 d1 = *(const i32x4*)(bp + 4);
            unpack2(d0, d1, bh[ns], bl[ns]);
        }
#pragma unroll
        for (int ms = 0; ms < 8; ms++) {
            const unsigned* ap = Sx + (long)(m0 + ms * 16 + lr) * 512 + k0 + lg * 8;
            i32x4 d0 = *(const i32x4*)ap;
            i32x4 d1 = *(const i32x4*)(ap + 4);
            bf16x8 ah, al; unpack2(d0, d1, ah, al);
#pragma unroll
            for (int ns = 0; ns < 2; ns++) {
                acc[ms][ns] = __builtin_amdgcn_mfma_f32_16x16x32_bf16(ah, bh[ns], acc[ms][ns], 0, 0, 0);
                acc[ms][ns] = __builtin_amdgcn_mfma_f32_16x16x32_bf16(ah, bl[ns], acc[ms][ns], 0, 0, 0);
                acc[ms][ns] = __builtin_amdgcn_mfma_f32_16x16x32_bf16(al, bh[ns], acc[ms][ns], 0, 0, 0);
            }
        }
    }
    // write to LDS [n][m], float4-block rotated by n to avoid bank conflicts
#pragma unroll
    for (int ns = 0; ns < 2; ns++) {
        int n = n0 + ns * 16 + lr;
        float bias = b2[n];
#pragma unroll
        for (int ms = 0; ms < 8; ms++) {
            int blk = ((ms * 4 + lg) + n) & 31;
#pragma unroll
            for (int r = 0; r < 4; r++)
                T[n * 128 + blk * 4 + r] = acc[ms][ns][r] + bias;
        }
    }
    __syncthreads();
    // cooperative coalesced store to t2 (c-major)
#pragma unroll
    for (int i = 0; i < 16; i++) {
        int flat = i * 256 + tid;          // 0..4095
        int n = flat >> 5, q = flat & 31;
        const float4* src = (const float4*)&T[n * 128 + (((q + n) & 31) * 4)];
        float4 v = *src;
        *(float4*)(t2 + (long)n * 65536 + p0 + m0 + q * 4) = v;
    }
}

// ---------------------------------------------------------------- OXO: h += t2*W^T + b   (A from split t2, LDS transpose epilogue)
__global__ __launch_bounds__(256, 2)
void oxo_kernel(const unsigned* __restrict__ Tx, const unsigned* __restrict__ Bx,
                const float* __restrict__ ob, float* __restrict__ h) {
    __shared__ float T[128 * 128];
    int tid = threadIdx.x;
    int w = tid >> 6, l = tid & 63;
    int lr = l & 15, lg = l >> 4;
    int m0 = blockIdx.x * 128;                  // pixel tile, full batch
    int n0 = w * 32;
    f32x4 acc[8][2] = {};
    for (int k0 = 0; k0 < 128; k0 += 32) {
        bf16x8 bh[2], bl[2];
#pragma unroll
        for (int ns = 0; ns < 2; ns++) {
            const unsigned* bp = Bx + (n0 + ns * 16 + lr) * 128 + k0 + lg * 8;
            i32x4 d0 = *(const i32x4*)bp;
            i32x4 d1 = *(const i32x4*)(bp + 4);
            unpack2(d0, d1, bh[ns], bl[ns]);
        }
#pragma unroll
        for (int ms = 0; ms < 8; ms++) {
            const unsigned* ap = Tx + (long)(k0 + lg * 8) * 65536 + m0 + ms * 16 + lr;
            int d[8];
#pragma unroll
            for (int j = 0; j < 8; j++) d[j] = (int)ap[(long)j * 65536];
            bf16x8 ah, al; unpack8(d, ah, al);
#pragma unroll
            for (int ns = 0; ns < 2; ns++) {
                acc[ms][ns] = __builtin_amdgcn_mfma_f32_16x16x32_bf16(ah, bh[ns], acc[ms][ns], 0, 0, 0);
                acc[ms][ns] = __builtin_amdgcn_mfma_f32_16x16x32_bf16(ah, bl[ns], acc[ms][ns], 0, 0, 0);
                acc[ms][ns] = __builtin_amdgcn_mfma_f32_16x16x32_bf16(al, bh[ns], acc[ms][ns], 0, 0, 0);
            }
        }
    }
#pragma unroll
    for (int ns = 0; ns < 2; ns++) {
        int n = n0 + ns * 16 + lr;
#pragma unroll
        for (int ms = 0; ms < 8; ms++) {
            int blk = ((ms * 4 + lg) + n) & 31;
#pragma unroll
            for (int r = 0; r < 4; r++)
                T[n * 128 + blk * 4 + r] = acc[ms][ns][r];
        }
    }
    __syncthreads();
#pragma unroll
    for (int i = 0; i < 16; i++) {
        int flat = i * 256 + tid;
        int n = flat >> 5, q = flat & 31;
        const float4* src = (const float4*)&T[n * 128 + (((q + n) & 31) * 4)];
        float4 v = *src;
        float bias = ob[n];
        float* hp = h + (long)n * 65536 + m0 + q * 4;
        float4 hv = *(float4*)hp;
        hv.x += v.x + bias; hv.y += v.y + bias;
        hv.z += v.z + bias; hv.w += v.w + bias;
        *(float4*)hp = hv;
    }
}

// ---------------------------------------------------------------- row forward rfft (unchanged)
__global__ void fft_row_fwd(const float* __restrict__ in, float2* __restrict__ freq) {
    __shared__ float2 A[4][256];
    __shared__ float2 B[4][256];
    int tid = threadIdx.x;
    long rowbase = (long)blockIdx.x * 4;
    {
        int r = tid >> 6, l = tid & 63;
        const float4* src = (const float4*)(in + (rowbase + r) * 256);
        float4 v = src[l];
        A[r][l * 4 + 0] = make_float2(v.x, 0.f);
        A[r][l * 4 + 1] = make_float2(v.y, 0.f);
        A[r][l * 4 + 2] = make_float2(v.z, 0.f);
        A[r][l * 4 + 3] = make_float2(v.w, 0.f);
    }
    __syncthreads();
    float2 (*s)[256] = A; float2 (*d)[256] = B;
    for (int m = 1; m < 256; m <<= 1) {
#pragma unroll
        for (int q = 0; q < 2; q++) {
            int bf = tid + q * 256;
            int r = bf >> 7, i = bf & 127;
            int jm = i & ~(m - 1);
            float2 c0 = s[r][i], c1 = s[r][i + 128];
            float ang = -(PI2 / 256.f) * (float)jm;
            float sn, cs; __sincosf(ang, &sn, &cs);
            float2 df = make_float2(c0.x - c1.x, c0.y - c1.y);
            d[r][i + jm]     = make_float2(c0.x + c1.x, c0.y + c1.y);
            d[r][i + jm + m] = make_float2(cs * df.x - sn * df.y, cs * df.y + sn * df.x);
        }
        __syncthreads();
        float2 (*tmp)[256] = s; s = d; d = tmp;
    }
    for (int q = tid; q < 4 * 129; q += 256) {
        int r = q / 129; int k = q - r * 129;
        freq[(rowbase + r) * 129 + k] = s[r][k];
    }
}

// ---------------------------------------------------------------- column FFT + filter + inverse (unchanged)
__global__ void fft_col(float2* __restrict__ freq, const float* __restrict__ mags,
                        const float* __restrict__ phases) {
    __shared__ float2 A[8][256];
    __shared__ float2 B[8][256];
    int tid = threadIdx.x;
    int img = blockIdx.x / 17;
    int kt  = blockIdx.x % 17;
    int kx0 = kt * 8;
    long base = (long)img * 256 * 129;
#pragma unroll
    for (int q = 0; q < 8; q++) {
        int e = tid + q * 256;
        int cl = e & 7, y = e >> 3;
        int kx = kx0 + cl;
        if (kx < 129) A[cl][y] = freq[base + (long)y * 129 + kx];
    }
    __syncthreads();
    float2 (*s)[256] = A; float2 (*d)[256] = B;
    for (int m = 1; m < 256; m <<= 1) {
#pragma unroll
        for (int q = 0; q < 4; q++) {
            int bf = tid + q * 256;
            int cl = bf >> 7, i = bf & 127;
            int jm = i & ~(m - 1);
            float2 c0 = s[cl][i], c1 = s[cl][i + 128];
            float ang = -(PI2 / 256.f) * (float)jm;
            float sn, cs; __sincosf(ang, &sn, &cs);
            float2 df = make_float2(c0.x - c1.x, c0.y - c1.y);
            d[cl][i + jm]     = make_float2(c0.x + c1.x, c0.y + c1.y);
            d[cl][i + jm + m] = make_float2(cs * df.x - sn * df.y, cs * df.y + sn * df.x);
        }
        __syncthreads();
        float2 (*tmp)[256] = s; s = d; d = tmp;
    }
#pragma unroll
    for (int q = 0; q < 8; q++) {
        int e = tid + q * 256;
        int cl = e & 7, ky = e >> 3;
        int kx = kx0 + cl;
        float2 v = s[cl][ky];
        float2 r = make_float2(0.f, 0.f);
        if (kx < 129) {
            int ry = ky < 128 ? ky : ky - 256;
            if (kx * kx + ry * ry <= 16384) {
                long fi = ((long)img * 256 + ky) * 129 + kx;
                float mg = mags[fi], ph = phases[fi];
                float sg = 1.0f / (1.0f + __expf(-mg));
                float sn, cs; __sincosf(ph, &sn, &cs);
                float fr = sg * cs, fim = sg * sn;
                r = make_float2(v.x * fr - v.y * fim, v.x * fim + v.y * fr);
            }
        }
        s[cl][ky] = r;
    }
    __syncthreads();
    for (int m = 1; m < 256; m <<= 1) {
#pragma unroll
        for (int q = 0; q < 4; q++) {
            int bf = tid + q * 256;
            int cl = bf >> 7, i = bf & 127;
            int jm = i & ~(m - 1);
            float2 c0 = s[cl][i], c1 = s[cl][i + 128];
            float ang = (PI2 / 256.f) * (float)jm;
            float sn, cs; __sincosf(ang, &sn, &cs);
            float2 df = make_float2(c0.x - c1.x, c0.y - c1.y);
            d[cl][i + jm]     = make_float2(c0.x + c1.x, c0.y + c1.y);
            d[cl][i + jm + m] = make_float2(cs * df.x - sn * df.y, cs * df.y + sn * df.x);
        }
        __syncthreads();
        float2 (*tmp)[256] = s; s = d; d = tmp;
    }
#pragma unroll
    for (int q = 0; q < 8; q++) {
        int e = tid + q * 256;
        int cl = e & 7, y = e >> 3;
        int kx = kx0 + cl;
        if (kx < 129) freq[base + (long)y * 129 + kx] = s[cl][y];
    }
}

// ---------------------------------------------------------------- row inverse rfft (unchanged)
__global__ void fft_row_inv(const float2* __restrict__ freq, float* __restrict__ out) {
    __shared__ float2 A[4][256];
    __shared__ float2 B[4][256];
    int tid = threadIdx.x;
    long rowbase = (long)blockIdx.x * 4;
#pragma unroll
    for (int q = 0; q < 4; q++) {
        int e = tid + q * 256;
        int r = e >> 8, xx = e & 255;
        const float2* fr = freq + (rowbase + r) * 129;
        float2 v;
        if (xx <= 128) v = fr[xx];
        else { float2 w2 = fr[256 - xx]; v = make_float2(w2.x, -w2.y); }
        A[r][xx] = v;
    }
    __syncthreads();
    float2 (*s)[256] = A; float2 (*d)[256] = B;
    for (int m = 1; m < 256; m <<= 1) {
#pragma unroll
        for (int q = 0; q < 2; q++) {
            int bf = tid + q * 256;
            int r = bf >> 7, i = bf & 127;
            int jm = i & ~(m - 1);
            float2 c0 = s[r][i], c1 = s[r][i + 128];
            float ang = (PI2 / 256.f) * (float)jm;
            float sn, cs; __sincosf(ang, &sn, &cs);
            float2 df = make_float2(c0.x - c1.x, c0.y - c1.y);
            d[r][i + jm]     = make_float2(c0.x + c1.x, c0.y + c1.y);
            d[r][i + jm + m] = make_float2(cs * df.x - sn * df.y, cs * df.y + sn * df.x);
        }
        __syncthreads();
        float2 (*tmp)[256] = s; s = d; d = tmp;
    }
    {
        int r = tid >> 6, l = tid & 63;
        float4* dst = (float4*)(out + (rowbase + r) * 256);
        const float sc = 1.0f / 65536.0f;
        float4 v;
        v.x = s[r][l * 4 + 0].x * sc;
        v.y = s[r][l * 4 + 1].x * sc;
        v.z = s[r][l * 4 + 2].x * sc;
        v.w = s[r][l * 4 + 3].x * sc;
        dst[l] = v;
    }
}

// ---------------------------------------------------------------- decoder (unchanged)
__global__ void dec_kernel(const float* __restrict__ h, const float* __restrict__ w,
                           const float* __restrict__ b, float* __restrict__ out) {
    int t = blockIdx.x * 256 + threadIdx.x;
    int bb = t >> 16, p = t & 65535;
    const float* hb = h + (long)bb * 128 * 65536 + p;
    float a0 = b[0], a1 = b[1];
    float a0b = 0.f, a1b = 0.f;
#pragma unroll 4
    for (int c = 0; c < 128; c += 2) {
        float h0 = hb[(long)c * 65536];
        float h1 = hb[(long)(c + 1) * 65536];
        a0  += w[c] * h0;        a1  += w[128 + c] * h0;
        a0b += w[c + 1] * h1;    a1b += w[128 + c + 1] * h1;
    }
    out[((long)bb * 2 + 0) * 65536 + p] = (a0 + a0b) * 0.125f;
    out[((long)bb * 2 + 1) * 65536 + p] = (a1 + a1b) * 0.125f;
}

// ---------------------------------------------------------------- launch
extern "C" void kernel_launch(void* const* d_in, const int* in_sizes, int n_in,
                              void* d_out, int out_size, void* d_ws, size_t ws_size,
                              hipStream_t stream) {
    const float* x        = (const float*)d_in[0];
    const float* enc_w    = (const float*)d_in[1];
    const float* enc_b    = (const float*)d_in[2];
    const float* pos_emb  = (const float*)d_in[3];
    const float* mlp_w1   = (const float*)d_in[4];
    const float* mlp_b1   = (const float*)d_in[5];
    const float* mlp_w2   = (const float*)d_in[6];
    const float* mlp_b2   = (const float*)d_in[7];
    const float* spec_mag = (const float*)d_in[8];
    const float* spec_ph  = (const float*)d_in[9];
    const float* oxo_w    = (const float*)d_in[10];
    const float* oxo_b    = (const float*)d_in[11];
    const float* dec_w    = (const float*)d_in[12];
    const float* dec_b    = (const float*)d_in[13];
    float* outp = (float*)d_out;

    // ws layout (floats):
    //  h        33,554,432   (128 MB, persistent, c-major [b][c][p])
    //  t2/Ax     8,388,608   ( 32 MB, per-batch real space fp32 / split-h dwords, aliased)
    //  freqrgn   8,454,144   ( 33.8 MB: FFT complex OR Sx hidden OR Tx split-t2)
    //  Wx1/Wx2/Wox  147,456  ( 0.6 MB, per-layer split weights)
    const size_t WS_NEEDED = 201850880ULL;
    if (ws_size < WS_NEEDED) {
        sentinel_kernel<<<(out_size + 255) / 256, 256, 0, stream>>>(outp, out_size);
        return;
    }

    float*    h    = (float*)d_ws;
    float*    t2   = h + 33554432;
    unsigned* Ax   = (unsigned*)t2;                       // alias
    float*    frgn = t2 + 8388608;
    float2*   freq = (float2*)frgn;
    unsigned* Sx   = (unsigned*)frgn;                     // 8,388,608 dwords
    unsigned* Tx   = (unsigned*)frgn;                     // 8,388,608 dwords
    unsigned* Wx1  = (unsigned*)(frgn + 8454144);
    unsigned* Wx2  = Wx1 + 65536;
    unsigned* Wox  = Wx2 + 65536;

    enc_kernel<<<131072, 256, 0, stream>>>(x, enc_w, enc_b, pos_emb, h);

    for (int l = 0; l < 4; l++) {
        split_kernel<<<64, 256, 0, stream>>>(mlp_w1 + (long)l * 65536, Wx1);
        split_kernel<<<64, 256, 0, stream>>>(mlp_w2 + (long)l * 65536, Wx2);
        split_kernel<<<16, 256, 0, stream>>>(oxo_w + (long)l * 16384, Wox);
        const float* b1l = mlp_b1 + l * 512;
        const float* b2l = mlp_b2 + l * 128;
        const float* mgl = spec_mag + (long)l * 4227072;
        const float* phl = spec_ph  + (long)l * 4227072;
        const float* obl = oxo_b + l * 128;
        for (int b = 0; b < 4; b++) {
            float* hb = h + (long)b * 8388608;
            split_kernel<<<8192, 256, 0, stream>>>(hb, Ax);      // h -> split, into t2 region
            for (int c = 0; c < 4; c++) {
                int p0 = c * 16384;
                gemm1_kernel<<<dim3(128, 4), 256, 0, stream>>>(Ax, Wx1, b1l, Sx, p0);
                gemm2_kernel<<<128, 256, 0, stream>>>(Sx, Wx2, b2l, t2, p0);
            }
            fft_row_fwd<<<8192, 256, 0, stream>>>(t2, freq);
            fft_col<<<128 * 17, 256, 0, stream>>>(freq, mgl, phl);
            fft_row_inv<<<8192, 256, 0, stream>>>(freq, t2);
            split_kernel<<<8192, 256, 0, stream>>>(t2, Tx);      // t2 -> split, into freq region
            oxo_kernel<<<512, 256, 0, stream>>>(Tx, Wox, obl, hb);
        }
    }

    dec_kernel<<<1024, 256, 0, stream>>>(h, dec_w, dec_b, outp);
}

// Round 4
// 6259.898 us; speedup vs baseline: 7.1128x; 1.0462x over previous
//
#include <hip/hip_runtime.h>
#include <math.h>

#define PI2 6.2831853071795864769f

typedef short bf16x8 __attribute__((ext_vector_type(8)));
typedef float f32x4 __attribute__((ext_vector_type(4)));
typedef int   i32x4 __attribute__((ext_vector_type(4)));

// ---------------------------------------------------------------- helpers
// split fp32 v into bf16 hi (rne) and bf16 lo (rne of v-hi), packed hi | lo<<16
__device__ inline unsigned splitf(float v) {
    unsigned u  = __float_as_uint(v);
    unsigned r  = (u + 0x7fffu + ((u >> 16) & 1u)) >> 16;
    float hi    = __uint_as_float(r << 16);
    float lof   = v - hi;
    unsigned u2 = __float_as_uint(lof);
    unsigned r2 = (u2 + 0x7fffu + ((u2 >> 16) & 1u)) >> 16;
    return (r & 0xffffu) | (r2 << 16);
}
// unpack split dword back to fp32 (exact value of hi+lo)
__device__ inline float upk(unsigned w) {
    return __uint_as_float(w << 16) + __uint_as_float(w & 0xffff0000u);
}

union VecU { i32x4 i; bf16x8 s; };

__device__ inline void unpack2(i32x4 d0, i32x4 d1, bf16x8& hi, bf16x8& lo) {
    VecU h, l;
    h.i.x = __builtin_amdgcn_perm(d0.y, d0.x, 0x05040100);
    h.i.y = __builtin_amdgcn_perm(d0.w, d0.z, 0x05040100);
    h.i.z = __builtin_amdgcn_perm(d1.y, d1.x, 0x05040100);
    h.i.w = __builtin_amdgcn_perm(d1.w, d1.z, 0x05040100);
    l.i.x = __builtin_amdgcn_perm(d0.y, d0.x, 0x07060302);
    l.i.y = __builtin_amdgcn_perm(d0.w, d0.z, 0x07060302);
    l.i.z = __builtin_amdgcn_perm(d1.y, d1.x, 0x07060302);
    l.i.w = __builtin_amdgcn_perm(d1.w, d1.z, 0x07060302);
    hi = h.s; lo = l.s;
}

__device__ inline void unpack8(const int* d, bf16x8& hi, bf16x8& lo) {
    VecU h, l;
    h.i.x = __builtin_amdgcn_perm(d[1], d[0], 0x05040100);
    h.i.y = __builtin_amdgcn_perm(d[3], d[2], 0x05040100);
    h.i.z = __builtin_amdgcn_perm(d[5], d[4], 0x05040100);
    h.i.w = __builtin_amdgcn_perm(d[7], d[6], 0x05040100);
    l.i.x = __builtin_amdgcn_perm(d[1], d[0], 0x07060302);
    l.i.y = __builtin_amdgcn_perm(d[3], d[2], 0x07060302);
    l.i.z = __builtin_amdgcn_perm(d[5], d[4], 0x07060302);
    l.i.w = __builtin_amdgcn_perm(d[7], d[6], 0x07060302);
    hi = h.s; lo = l.s;
}

// ---------------------------------------------------------------- sentinel
__global__ void sentinel_kernel(float* __restrict__ out, int n) {
    int t = blockIdx.x * 256 + threadIdx.x;
    if (t < n) out[t] = 12345.0f;
}

// ---------------------------------------------------------------- split: fp32 -> interleaved bf16 hi/lo dwords (weights only)
__global__ void split_kernel(const float* __restrict__ in, unsigned* __restrict__ out) {
    long q = (long)blockIdx.x * 256 + threadIdx.x;
    const float4* ip = (const float4*)in;
    float4 v = ip[q];
    i32x4 o;
    o.x = (int)splitf(v.x); o.y = (int)splitf(v.y);
    o.z = (int)splitf(v.z); o.w = (int)splitf(v.w);
    ((i32x4*)out)[q] = o;
}

// ---------------------------------------------------------------- encoder: writes h in SPLIT format, vectorized x4
__global__ void enc_kernel(const float* __restrict__ x, const float* __restrict__ w,
                           const float* __restrict__ b, const float* __restrict__ pos,
                           unsigned* __restrict__ h) {
    long t = (long)blockIdx.x * 256 + threadIdx.x;   // quad index 0..8388607
    int pq = (int)(t & 16383);
    int c  = (int)((t >> 14) & 127);
    int bb = (int)(t >> 21);
    float4 x0 = *(const float4*)(x + ((long)bb * 2 + 0) * 65536 + pq * 4);
    float4 x1 = *(const float4*)(x + ((long)bb * 2 + 1) * 65536 + pq * 4);
    float4 pv = *(const float4*)(pos + (long)c * 65536 + pq * 4);
    float w0 = w[c * 2], w1 = w[c * 2 + 1], bc = b[c];
    uint4 o;
    o.x = splitf((w0 * x0.x + w1 * x1.x + bc) * 8.0f + pv.x);
    o.y = splitf((w0 * x0.y + w1 * x1.y + bc) * 8.0f + pv.y);
    o.z = splitf((w0 * x0.z + w1 * x1.z + bc) * 8.0f + pv.z);
    o.w = splitf((w0 * x0.w + w1 * x1.w + bc) * 8.0f + pv.w);
    *(uint4*)(h + t * 4) = o;
}

// ---------------------------------------------------------------- GEMM1: hidden = silu(h*W1^T + b1), split-store
__global__ __launch_bounds__(256, 2)
void gemm1_kernel(const unsigned* __restrict__ Ax, const unsigned* __restrict__ Bx,
                  const float* __restrict__ b1, unsigned* __restrict__ Sx, int p0) {
    int tid = threadIdx.x;
    int w = tid >> 6, l = tid & 63;
    int lr = l & 15, lg = l >> 4;
    int m0 = blockIdx.x * 128;
    int n0 = blockIdx.y * 128 + w * 32;
    f32x4 acc[8][2] = {};
    for (int k0 = 0; k0 < 128; k0 += 32) {
        bf16x8 bh[2], bl[2];
#pragma unroll
        for (int ns = 0; ns < 2; ns++) {
            const unsigned* bp = Bx + (n0 + ns * 16 + lr) * 128 + k0 + lg * 8;
            i32x4 d0 = *(const i32x4*)bp;
            i32x4 d1 = *(const i32x4*)(bp + 4);
            unpack2(d0, d1, bh[ns], bl[ns]);
        }
#pragma unroll
        for (int ms = 0; ms < 8; ms++) {
            const unsigned* ap = Ax + (long)(k0 + lg * 8) * 65536 + p0 + m0 + ms * 16 + lr;
            int d[8];
#pragma unroll
            for (int j = 0; j < 8; j++) d[j] = (int)ap[(long)j * 65536];
            bf16x8 ah, al; unpack8(d, ah, al);
#pragma unroll
            for (int ns = 0; ns < 2; ns++) {
                acc[ms][ns] = __builtin_amdgcn_mfma_f32_16x16x32_bf16(ah, bh[ns], acc[ms][ns], 0, 0, 0);
                acc[ms][ns] = __builtin_amdgcn_mfma_f32_16x16x32_bf16(ah, bl[ns], acc[ms][ns], 0, 0, 0);
                acc[ms][ns] = __builtin_amdgcn_mfma_f32_16x16x32_bf16(al, bh[ns], acc[ms][ns], 0, 0, 0);
            }
        }
    }
#pragma unroll
    for (int ns = 0; ns < 2; ns++) {
        int hd = n0 + ns * 16 + lr;
        float bias = b1[hd];
#pragma unroll
        for (int ms = 0; ms < 8; ms++) {
#pragma unroll
            for (int r = 0; r < 4; r++) {
                float pre = acc[ms][ns][r] + bias;
                float s = pre / (1.0f + __expf(-pre));
                int pix = m0 + ms * 16 + lg * 4 + r;
                Sx[(long)pix * 512 + hd] = splitf(s);
            }
        }
    }
}

// ---------------------------------------------------------------- GEMM2: t2 = hidden*W2^T + b2  (c-major fp32 store via LDS)
__global__ __launch_bounds__(256, 2)
void gemm2_kernel(const unsigned* __restrict__ Sx, const unsigned* __restrict__ Bx,
                  const float* __restrict__ b2, float* __restrict__ t2, int p0) {
    __shared__ float T[128 * 128];
    int tid = threadIdx.x;
    int w = tid >> 6, l = tid & 63;
    int lr = l & 15, lg = l >> 4;
    int m0 = blockIdx.x * 128;
    int n0 = w * 32;
    f32x4 acc[8][2] = {};
    for (int k0 = 0; k0 < 512; k0 += 32) {
        bf16x8 bh[2], bl[2];
#pragma unroll
        for (int ns = 0; ns < 2; ns++) {
            const unsigned* bp = Bx + (n0 + ns * 16 + lr) * 512 + k0 + lg * 8;
            i32x4 d0 = *(const i32x4*)bp;
            i32x4 d1 = *(const i32x4*)(bp + 4);
            unpack2(d0, d1, bh[ns], bl[ns]);
        }
#pragma unroll
        for (int ms = 0; ms < 8; ms++) {
            const unsigned* ap = Sx + (long)(m0 + ms * 16 + lr) * 512 + k0 + lg * 8;
            i32x4 d0 = *(const i32x4*)ap;
            i32x4 d1 = *(const i32x4*)(ap + 4);
            bf16x8 ah, al; unpack2(d0, d1, ah, al);
#pragma unroll
            for (int ns = 0; ns < 2; ns++) {
                acc[ms][ns] = __builtin_amdgcn_mfma_f32_16x16x32_bf16(ah, bh[ns], acc[ms][ns], 0, 0, 0);
                acc[ms][ns] = __builtin_amdgcn_mfma_f32_16x16x32_bf16(ah, bl[ns], acc[ms][ns], 0, 0, 0);
                acc[ms][ns] = __builtin_amdgcn_mfma_f32_16x16x32_bf16(al, bh[ns], acc[ms][ns], 0, 0, 0);
            }
        }
    }
#pragma unroll
    for (int ns = 0; ns < 2; ns++) {
        int n = n0 + ns * 16 + lr;
        float bias = b2[n];
#pragma unroll
        for (int ms = 0; ms < 8; ms++) {
            int blk = ((ms * 4 + lg) + n) & 31;
#pragma unroll
            for (int r = 0; r < 4; r++)
                T[n * 128 + blk * 4 + r] = acc[ms][ns][r] + bias;
        }
    }
    __syncthreads();
#pragma unroll
    for (int i = 0; i < 16; i++) {
        int flat = i * 256 + tid;
        int n = flat >> 5, q = flat & 31;
        const float4* src = (const float4*)&T[n * 128 + (((q + n) & 31) * 4)];
        float4 v = *src;
        *(float4*)(t2 + (long)n * 65536 + p0 + m0 + q * 4) = v;
    }
}

// ---------------------------------------------------------------- OXO: h += t2*W^T + b   (h in split format)
__global__ __launch_bounds__(256, 2)
void oxo_kernel(const unsigned* __restrict__ Tx, const unsigned* __restrict__ Bx,
                const float* __restrict__ ob, unsigned* __restrict__ h) {
    __shared__ float T[128 * 128];
    int tid = threadIdx.x;
    int w = tid >> 6, l = tid & 63;
    int lr = l & 15, lg = l >> 4;
    int m0 = blockIdx.x * 128;
    int n0 = w * 32;
    f32x4 acc[8][2] = {};
    for (int k0 = 0; k0 < 128; k0 += 32) {
        bf16x8 bh[2], bl[2];
#pragma unroll
        for (int ns = 0; ns < 2; ns++) {
            const unsigned* bp = Bx + (n0 + ns * 16 + lr) * 128 + k0 + lg * 8;
            i32x4 d0 = *(const i32x4*)bp;
            i32x4 d1 = *(const i32x4*)(bp + 4);
            unpack2(d0, d1, bh[ns], bl[ns]);
        }
#pragma unroll
        for (int ms = 0; ms < 8; ms++) {
            const unsigned* ap = Tx + (long)(k0 + lg * 8) * 65536 + m0 + ms * 16 + lr;
            int d[8];
#pragma unroll
            for (int j = 0; j < 8; j++) d[j] = (int)ap[(long)j * 65536];
            bf16x8 ah, al; unpack8(d, ah, al);
#pragma unroll
            for (int ns = 0; ns < 2; ns++) {
                acc[ms][ns] = __builtin_amdgcn_mfma_f32_16x16x32_bf16(ah, bh[ns], acc[ms][ns], 0, 0, 0);
                acc[ms][ns] = __builtin_amdgcn_mfma_f32_16x16x32_bf16(ah, bl[ns], acc[ms][ns], 0, 0, 0);
                acc[ms][ns] = __builtin_amdgcn_mfma_f32_16x16x32_bf16(al, bh[ns], acc[ms][ns], 0, 0, 0);
            }
        }
    }
#pragma unroll
    for (int ns = 0; ns < 2; ns++) {
        int n = n0 + ns * 16 + lr;
#pragma unroll
        for (int ms = 0; ms < 8; ms++) {
            int blk = ((ms * 4 + lg) + n) & 31;
#pragma unroll
            for (int r = 0; r < 4; r++)
                T[n * 128 + blk * 4 + r] = acc[ms][ns][r];
        }
    }
    __syncthreads();
#pragma unroll
    for (int i = 0; i < 16; i++) {
        int flat = i * 256 + tid;
        int n = flat >> 5, q = flat & 31;
        const float4* src = (const float4*)&T[n * 128 + (((q + n) & 31) * 4)];
        float4 v = *src;
        float bias = ob[n];
        unsigned* hp = h + (long)n * 65536 + m0 + q * 4;
        uint4 hv = *(uint4*)hp;
        uint4 o;
        o.x = splitf(upk(hv.x) + v.x + bias);
        o.y = splitf(upk(hv.y) + v.y + bias);
        o.z = splitf(upk(hv.z) + v.z + bias);
        o.w = splitf(upk(hv.w) + v.w + bias);
        *(uint4*)hp = o;
    }
}

// ---------------------------------------------------------------- row forward rfft (twiddle table)
__global__ void fft_row_fwd(const float* __restrict__ in, float2* __restrict__ freq) {
    __shared__ float2 A[4][256];
    __shared__ float2 B[4][256];
    __shared__ float2 TW[128];
    int tid = threadIdx.x;
    long rowbase = (long)blockIdx.x * 4;
    if (tid < 128) {
        float sn, cs; __sincosf((PI2 / 256.f) * (float)tid, &sn, &cs);
        TW[tid] = make_float2(cs, sn);
    }
    {
        int r = tid >> 6, l = tid & 63;
        const float4* src = (const float4*)(in + (rowbase + r) * 256);
        float4 v = src[l];
        A[r][l * 4 + 0] = make_float2(v.x, 0.f);
        A[r][l * 4 + 1] = make_float2(v.y, 0.f);
        A[r][l * 4 + 2] = make_float2(v.z, 0.f);
        A[r][l * 4 + 3] = make_float2(v.w, 0.f);
    }
    __syncthreads();
    float2 (*s)[256] = A; float2 (*d)[256] = B;
    for (int m = 1; m < 256; m <<= 1) {
#pragma unroll
        for (int q = 0; q < 2; q++) {
            int bf = tid + q * 256;
            int r = bf >> 7, i = bf & 127;
            int jm = i & ~(m - 1);
            float2 c0 = s[r][i], c1 = s[r][i + 128];
            float2 t = TW[jm];
            float2 df = make_float2(c0.x - c1.x, c0.y - c1.y);
            d[r][i + jm]     = make_float2(c0.x + c1.x, c0.y + c1.y);
            d[r][i + jm + m] = make_float2(t.x * df.x + t.y * df.y, t.x * df.y - t.y * df.x);
        }
        __syncthreads();
        float2 (*tmp)[256] = s; s = d; d = tmp;
    }
    for (int q = tid; q < 4 * 129; q += 256) {
        int r = q / 129; int k = q - r * 129;
        freq[(rowbase + r) * 129 + k] = s[r][k];
    }
}

// ---------------------------------------------------------------- column FFT + filter + inverse (twiddle table)
__global__ void fft_col(float2* __restrict__ freq, const float* __restrict__ mags,
                        const float* __restrict__ phases) {
    __shared__ float2 A[8][256];
    __shared__ float2 B[8][256];
    __shared__ float2 TW[128];
    int tid = threadIdx.x;
    int img = blockIdx.x / 17;
    int kt  = blockIdx.x % 17;
    int kx0 = kt * 8;
    long base = (long)img * 256 * 129;
    if (tid < 128) {
        float sn, cs; __sincosf((PI2 / 256.f) * (float)tid, &sn, &cs);
        TW[tid] = make_float2(cs, sn);
    }
#pragma unroll
    for (int q = 0; q < 8; q++) {
        int e = tid + q * 256;
        int cl = e & 7, y = e >> 3;
        int kx = kx0 + cl;
        if (kx < 129) A[cl][y] = freq[base + (long)y * 129 + kx];
    }
    __syncthreads();
    float2 (*s)[256] = A; float2 (*d)[256] = B;
    for (int m = 1; m < 256; m <<= 1) {           // forward
#pragma unroll
        for (int q = 0; q < 4; q++) {
            int bf = tid + q * 256;
            int cl = bf >> 7, i = bf & 127;
            int jm = i & ~(m - 1);
            float2 c0 = s[cl][i], c1 = s[cl][i + 128];
            float2 t = TW[jm];
            float2 df = make_float2(c0.x - c1.x, c0.y - c1.y);
            d[cl][i + jm]     = make_float2(c0.x + c1.x, c0.y + c1.y);
            d[cl][i + jm + m] = make_float2(t.x * df.x + t.y * df.y, t.x * df.y - t.y * df.x);
        }
        __syncthreads();
        float2 (*tmp)[256] = s; s = d; d = tmp;
    }
#pragma unroll
    for (int q = 0; q < 8; q++) {
        int e = tid + q * 256;
        int cl = e & 7, ky = e >> 3;
        int kx = kx0 + cl;
        float2 v = s[cl][ky];
        float2 r = make_float2(0.f, 0.f);
        if (kx < 129) {
            int ry = ky < 128 ? ky : ky - 256;
            if (kx * kx + ry * ry <= 16384) {
                long fi = ((long)img * 256 + ky) * 129 + kx;
                float mg = mags[fi], ph = phases[fi];
                float sg = 1.0f / (1.0f + __expf(-mg));
                float sn, cs; __sincosf(ph, &sn, &cs);
                float fr = sg * cs, fim = sg * sn;
                r = make_float2(v.x * fr - v.y * fim, v.x * fim + v.y * fr);
            }
        }
        s[cl][ky] = r;
    }
    __syncthreads();
    for (int m = 1; m < 256; m <<= 1) {           // inverse
#pragma unroll
        for (int q = 0; q < 4; q++) {
            int bf = tid + q * 256;
            int cl = bf >> 7, i = bf & 127;
            int jm = i & ~(m - 1);
            float2 c0 = s[cl][i], c1 = s[cl][i + 128];
            float2 t = TW[jm];
            float2 df = make_float2(c0.x - c1.x, c0.y - c1.y);
            d[cl][i + jm]     = make_float2(c0.x + c1.x, c0.y + c1.y);
            d[cl][i + jm + m] = make_float2(t.x * df.x - t.y * df.y, t.x * df.y + t.y * df.x);
        }
        __syncthreads();
        float2 (*tmp)[256] = s; s = d; d = tmp;
    }
#pragma unroll
    for (int q = 0; q < 8; q++) {
        int e = tid + q * 256;
        int cl = e & 7, y = e >> 3;
        int kx = kx0 + cl;
        if (kx < 129) freq[base + (long)y * 129 + kx] = s[cl][y];
    }
}

// ---------------------------------------------------------------- row inverse rfft (twiddle table, SPLIT output)
__global__ void fft_row_inv(const float2* __restrict__ freq, unsigned* __restrict__ out) {
    __shared__ float2 A[4][256];
    __shared__ float2 B[4][256];
    __shared__ float2 TW[128];
    int tid = threadIdx.x;
    long rowbase = (long)blockIdx.x * 4;
    if (tid < 128) {
        float sn, cs; __sincosf((PI2 / 256.f) * (float)tid, &sn, &cs);
        TW[tid] = make_float2(cs, sn);
    }
#pragma unroll
    for (int q = 0; q < 4; q++) {
        int e = tid + q * 256;
        int r = e >> 8, xx = e & 255;
        const float2* fr = freq + (rowbase + r) * 129;
        float2 v;
        if (xx <= 128) v = fr[xx];
        else { float2 w2 = fr[256 - xx]; v = make_float2(w2.x, -w2.y); }
        A[r][xx] = v;
    }
    __syncthreads();
    float2 (*s)[256] = A; float2 (*d)[256] = B;
    for (int m = 1; m < 256; m <<= 1) {
#pragma unroll
        for (int q = 0; q < 2; q++) {
            int bf = tid + q * 256;
            int r = bf >> 7, i = bf & 127;
            int jm = i & ~(m - 1);
            float2 c0 = s[r][i], c1 = s[r][i + 128];
            float2 t = TW[jm];
            float2 df = make_float2(c0.x - c1.x, c0.y - c1.y);
            d[r][i + jm]     = make_float2(c0.x + c1.x, c0.y + c1.y);
            d[r][i + jm + m] = make_float2(t.x * df.x - t.y * df.y, t.x * df.y + t.y * df.x);
        }
        __syncthreads();
        float2 (*tmp)[256] = s; s = d; d = tmp;
    }
    {
        int r = tid >> 6, l = tid & 63;
        const float sc = 1.0f / 65536.0f;
        uint4 o;
        o.x = splitf(s[r][l * 4 + 0].x * sc);
        o.y = splitf(s[r][l * 4 + 1].x * sc);
        o.z = splitf(s[r][l * 4 + 2].x * sc);
        o.w = splitf(s[r][l * 4 + 3].x * sc);
        *(uint4*)(out + (rowbase + r) * 256 + l * 4) = o;
    }
}

// ---------------------------------------------------------------- decoder (h in split format)
__global__ void dec_kernel(const unsigned* __restrict__ h, const float* __restrict__ w,
                           const float* __restrict__ b, float* __restrict__ out) {
    int t = blockIdx.x * 256 + threadIdx.x;
    int bb = t >> 16, p = t & 65535;
    const unsigned* hb = h + (long)bb * 8388608 + p;
    float a0 = b[0], a1 = b[1];
    float a0b = 0.f, a1b = 0.f;
#pragma unroll 4
    for (int c = 0; c < 128; c += 2) {
        float h0 = upk(hb[(long)c * 65536]);
        float h1 = upk(hb[(long)(c + 1) * 65536]);
        a0  += w[c] * h0;        a1  += w[128 + c] * h0;
        a0b += w[c + 1] * h1;    a1b += w[128 + c + 1] * h1;
    }
    out[((long)bb * 2 + 0) * 65536 + p] = (a0 + a0b) * 0.125f;
    out[((long)bb * 2 + 1) * 65536 + p] = (a1 + a1b) * 0.125f;
}

// ---------------------------------------------------------------- launch
extern "C" void kernel_launch(void* const* d_in, const int* in_sizes, int n_in,
                              void* d_out, int out_size, void* d_ws, size_t ws_size,
                              hipStream_t stream) {
    const float* x        = (const float*)d_in[0];
    const float* enc_w    = (const float*)d_in[1];
    const float* enc_b    = (const float*)d_in[2];
    const float* pos_emb  = (const float*)d_in[3];
    const float* mlp_w1   = (const float*)d_in[4];
    const float* mlp_b1   = (const float*)d_in[5];
    const float* mlp_w2   = (const float*)d_in[6];
    const float* mlp_b2   = (const float*)d_in[7];
    const float* spec_mag = (const float*)d_in[8];
    const float* spec_ph  = (const float*)d_in[9];
    const float* oxo_w    = (const float*)d_in[10];
    const float* oxo_b    = (const float*)d_in[11];
    const float* dec_w    = (const float*)d_in[12];
    const float* dec_b    = (const float*)d_in[13];
    float* outp = (float*)d_out;

    // ws layout (4B units):
    //  h (split dwords)  33,554,432   (128 MB, persistent)
    //  t2 region          8,388,608   ( 32 MB: fp32 gemm2-out/fft-in, then split irfft-out)
    //  frgn               8,454,144   ( 33.8 MB: freq complex OR Sx hidden)
    //  Wx1/Wx2/Wox          147,456
    const size_t WS_NEEDED = 201850880ULL;
    if (ws_size < WS_NEEDED) {
        sentinel_kernel<<<(out_size + 255) / 256, 256, 0, stream>>>(outp, out_size);
        return;
    }

    unsigned* h    = (unsigned*)d_ws;
    float*    t2   = (float*)(h + 33554432);
    unsigned* TxO  = (unsigned*)t2;                      // alias: split irfft output
    float*    frgn = t2 + 8388608;
    float2*   freq = (float2*)frgn;
    unsigned* Sx   = (unsigned*)frgn;
    unsigned* Wx1  = (unsigned*)(frgn + 8454144);
    unsigned* Wx2  = Wx1 + 65536;
    unsigned* Wox  = Wx2 + 65536;

    enc_kernel<<<32768, 256, 0, stream>>>(x, enc_w, enc_b, pos_emb, h);

    for (int l = 0; l < 4; l++) {
        split_kernel<<<64, 256, 0, stream>>>(mlp_w1 + (long)l * 65536, Wx1);
        split_kernel<<<64, 256, 0, stream>>>(mlp_w2 + (long)l * 65536, Wx2);
        split_kernel<<<16, 256, 0, stream>>>(oxo_w + (long)l * 16384, Wox);
        const float* b1l = mlp_b1 + l * 512;
        const float* b2l = mlp_b2 + l * 128;
        const float* mgl = spec_mag + (long)l * 4227072;
        const float* phl = spec_ph  + (long)l * 4227072;
        const float* obl = oxo_b + l * 128;
        for (int b = 0; b < 4; b++) {
            unsigned* hb = h + (long)b * 8388608;
            for (int c = 0; c < 4; c++) {
                int p0 = c * 16384;
                gemm1_kernel<<<dim3(128, 4), 256, 0, stream>>>(hb, Wx1, b1l, Sx, p0);
                gemm2_kernel<<<128, 256, 0, stream>>>(Sx, Wx2, b2l, t2, p0);
            }
            fft_row_fwd<<<8192, 256, 0, stream>>>(t2, freq);
            fft_col<<<128 * 17, 256, 0, stream>>>(freq, mgl, phl);
            fft_row_inv<<<8192, 256, 0, stream>>>(freq, TxO);
            oxo_kernel<<<512, 256, 0, stream>>>(TxO, Wox, obl, hb);
        }
    }

    dec_kernel<<<1024, 256, 0, stream>>>(h, dec_w, dec_b, outp);
}

// Round 5
// 4357.949 us; speedup vs baseline: 10.2170x; 1.4364x over previous
//
#include <hip/hip_runtime.h>
#include <math.h>

#define PI2 6.2831853071795864769f

typedef short bf16x8 __attribute__((ext_vector_type(8)));
typedef float f32x4 __attribute__((ext_vector_type(4)));
typedef int   i32x4 __attribute__((ext_vector_type(4)));

// ---------------------------------------------------------------- helpers
__device__ inline unsigned splitf(float v) {
    unsigned u  = __float_as_uint(v);
    unsigned r  = (u + 0x7fffu + ((u >> 16) & 1u)) >> 16;
    float hi    = __uint_as_float(r << 16);
    float lof   = v - hi;
    unsigned u2 = __float_as_uint(lof);
    unsigned r2 = (u2 + 0x7fffu + ((u2 >> 16) & 1u)) >> 16;
    return (r & 0xffffu) | (r2 << 16);
}
__device__ inline float upk(unsigned w) {
    return __uint_as_float(w << 16) + __uint_as_float(w & 0xffff0000u);
}

union VecU { i32x4 i; bf16x8 s; };

__device__ inline void unpack2(i32x4 d0, i32x4 d1, bf16x8& hi, bf16x8& lo) {
    VecU h, l;
    h.i.x = __builtin_amdgcn_perm(d0.y, d0.x, 0x05040100);
    h.i.y = __builtin_amdgcn_perm(d0.w, d0.z, 0x05040100);
    h.i.z = __builtin_amdgcn_perm(d1.y, d1.x, 0x05040100);
    h.i.w = __builtin_amdgcn_perm(d1.w, d1.z, 0x05040100);
    l.i.x = __builtin_amdgcn_perm(d0.y, d0.x, 0x07060302);
    l.i.y = __builtin_amdgcn_perm(d0.w, d0.z, 0x07060302);
    l.i.z = __builtin_amdgcn_perm(d1.y, d1.x, 0x07060302);
    l.i.w = __builtin_amdgcn_perm(d1.w, d1.z, 0x07060302);
    hi = h.s; lo = l.s;
}

__device__ inline void unpack8(const int* d, bf16x8& hi, bf16x8& lo) {
    VecU h, l;
    h.i.x = __builtin_amdgcn_perm(d[1], d[0], 0x05040100);
    h.i.y = __builtin_amdgcn_perm(d[3], d[2], 0x05040100);
    h.i.z = __builtin_amdgcn_perm(d[5], d[4], 0x05040100);
    h.i.w = __builtin_amdgcn_perm(d[7], d[6], 0x05040100);
    l.i.x = __builtin_amdgcn_perm(d[1], d[0], 0x07060302);
    l.i.y = __builtin_amdgcn_perm(d[3], d[2], 0x07060302);
    l.i.z = __builtin_amdgcn_perm(d[5], d[4], 0x07060302);
    l.i.w = __builtin_amdgcn_perm(d[7], d[6], 0x07060302);
    hi = h.s; lo = l.s;
}

// ---------------------------------------------------------------- sentinel
__global__ void sentinel_kernel(float* __restrict__ out, int n) {
    int t = blockIdx.x * 256 + threadIdx.x;
    if (t < n) out[t] = 12345.0f;
}

// ---------------------------------------------------------------- split (weights)
__global__ void split_kernel(const float* __restrict__ in, unsigned* __restrict__ out) {
    long q = (long)blockIdx.x * 256 + threadIdx.x;
    const float4* ip = (const float4*)in;
    float4 v = ip[q];
    i32x4 o;
    o.x = (int)splitf(v.x); o.y = (int)splitf(v.y);
    o.z = (int)splitf(v.z); o.w = (int)splitf(v.w);
    ((i32x4*)out)[q] = o;
}

// ---------------------------------------------------------------- encoder: h in SPLIT format
__global__ void enc_kernel(const float* __restrict__ x, const float* __restrict__ w,
                           const float* __restrict__ b, const float* __restrict__ pos,
                           unsigned* __restrict__ h) {
    long t = (long)blockIdx.x * 256 + threadIdx.x;   // quad index
    int pq = (int)(t & 16383);
    int c  = (int)((t >> 14) & 127);
    int bb = (int)(t >> 21);
    float4 x0 = *(const float4*)(x + ((long)bb * 2 + 0) * 65536 + pq * 4);
    float4 x1 = *(const float4*)(x + ((long)bb * 2 + 1) * 65536 + pq * 4);
    float4 pv = *(const float4*)(pos + (long)c * 65536 + pq * 4);
    float w0 = w[c * 2], w1 = w[c * 2 + 1], bc = b[c];
    uint4 o;
    o.x = splitf((w0 * x0.x + w1 * x1.x + bc) * 8.0f + pv.x);
    o.y = splitf((w0 * x0.y + w1 * x1.y + bc) * 8.0f + pv.y);
    o.z = splitf((w0 * x0.z + w1 * x1.z + bc) * 8.0f + pv.z);
    o.w = splitf((w0 * x0.w + w1 * x1.w + bc) * 8.0f + pv.w);
    *(uint4*)(h + t * 4) = o;
}

// ---------------------------------------------------------------- fused MLP: t2 = W2*silu(W1*h+b1)+b2
// 64 pixels per block; A-frags register-resident; hidden chunks (128 hd) via LDS.
__global__ __launch_bounds__(256, 1)
void mlp_fused(const unsigned* __restrict__ Ax, const unsigned* __restrict__ W1x,
               const float* __restrict__ b1, const unsigned* __restrict__ W2x,
               const float* __restrict__ b2, float* __restrict__ t2) {
    __shared__ unsigned LB[8704];     // hidden[64][132] dw  /  T[128][68] floats
    int tid = threadIdx.x;
    int w = tid >> 6, l = tid & 63;
    int lr = l & 15, lg = l >> 4;
    int p0 = blockIdx.x * 64;

    // load A (split h): apk[ms][ks][j]  -> 128 VGPR
    unsigned apk[4][4][8];
#pragma unroll
    for (int ms = 0; ms < 4; ms++)
#pragma unroll
        for (int ks = 0; ks < 4; ks++) {
            const unsigned* ap = Ax + (long)(ks * 32 + lg * 8) * 65536 + p0 + ms * 16 + lr;
#pragma unroll
            for (int j = 0; j < 8; j++) apk[ms][ks][j] = ap[(long)j * 65536];
        }

    f32x4 acc2[4][2] = {};
#pragma unroll 1
    for (int c = 0; c < 4; c++) {
        // ---- gemm1: hidden chunk = A * W1[c*128..+128]^T
        f32x4 acc1[4][2] = {};
#pragma unroll
        for (int ks = 0; ks < 4; ks++) {
            bf16x8 bh[2], bl[2];
#pragma unroll
            for (int ns = 0; ns < 2; ns++) {
                const unsigned* bp = W1x + (c * 128 + w * 32 + ns * 16 + lr) * 128 + ks * 32 + lg * 8;
                i32x4 d0 = *(const i32x4*)bp;
                i32x4 d1 = *(const i32x4*)(bp + 4);
                unpack2(d0, d1, bh[ns], bl[ns]);
            }
#pragma unroll
            for (int ms = 0; ms < 4; ms++) {
                bf16x8 ah, al; unpack8((const int*)apk[ms][ks], ah, al);
#pragma unroll
                for (int ns = 0; ns < 2; ns++) {
                    acc1[ms][ns] = __builtin_amdgcn_mfma_f32_16x16x32_bf16(ah, bh[ns], acc1[ms][ns], 0, 0, 0);
                    acc1[ms][ns] = __builtin_amdgcn_mfma_f32_16x16x32_bf16(ah, bl[ns], acc1[ms][ns], 0, 0, 0);
                    acc1[ms][ns] = __builtin_amdgcn_mfma_f32_16x16x32_bf16(al, bh[ns], acc1[ms][ns], 0, 0, 0);
                }
            }
        }
        // ---- silu + split -> LDS hidden[pix][132]
#pragma unroll
        for (int ns = 0; ns < 2; ns++) {
            int hdl = w * 32 + ns * 16 + lr;
            float bias = b1[c * 128 + hdl];
#pragma unroll
            for (int ms = 0; ms < 4; ms++)
#pragma unroll
                for (int r = 0; r < 4; r++) {
                    float pre = acc1[ms][ns][r] + bias;
                    float s = pre / (1.0f + __expf(-pre));
                    int pix = ms * 16 + lg * 4 + r;
                    LB[pix * 132 + hdl] = splitf(s);
                }
        }
        __syncthreads();
        // ---- gemm2 partial: acc2 += hidden * W2[:, c*128..+128]^T
#pragma unroll
        for (int ks2 = 0; ks2 < 4; ks2++) {
            bf16x8 bh[2], bl[2];
#pragma unroll
            for (int ns = 0; ns < 2; ns++) {
                const unsigned* bp = W2x + (w * 32 + ns * 16 + lr) * 512 + c * 128 + ks2 * 32 + lg * 8;
                i32x4 d0 = *(const i32x4*)bp;
                i32x4 d1 = *(const i32x4*)(bp + 4);
                unpack2(d0, d1, bh[ns], bl[ns]);
            }
#pragma unroll
            for (int ms = 0; ms < 4; ms++) {
                const i32x4* hp = (const i32x4*)&LB[(ms * 16 + lr) * 132 + ks2 * 32 + lg * 8];
                i32x4 d0 = hp[0], d1 = hp[1];
                bf16x8 ah, al; unpack2(d0, d1, ah, al);
#pragma unroll
                for (int ns = 0; ns < 2; ns++) {
                    acc2[ms][ns] = __builtin_amdgcn_mfma_f32_16x16x32_bf16(ah, bh[ns], acc2[ms][ns], 0, 0, 0);
                    acc2[ms][ns] = __builtin_amdgcn_mfma_f32_16x16x32_bf16(ah, bl[ns], acc2[ms][ns], 0, 0, 0);
                    acc2[ms][ns] = __builtin_amdgcn_mfma_f32_16x16x32_bf16(al, bh[ns], acc2[ms][ns], 0, 0, 0);
                }
            }
        }
        __syncthreads();
    }
    // ---- epilogue: T[n][68] then coalesced c-major store
    float* T = (float*)LB;
#pragma unroll
    for (int ns = 0; ns < 2; ns++) {
        int n = w * 32 + ns * 16 + lr;
        float bias = b2[n];
#pragma unroll
        for (int ms = 0; ms < 4; ms++)
#pragma unroll
            for (int r = 0; r < 4; r++) {
                int pix = ms * 16 + lg * 4 + r;
                T[n * 68 + pix] = acc2[ms][ns][r] + bias;
            }
    }
    __syncthreads();
#pragma unroll
    for (int i = 0; i < 8; i++) {
        int f = i * 256 + tid;             // 0..2047 float4s
        int n = f >> 4, q = f & 15;
        float4 v = *(const float4*)&T[n * 68 + q * 4];
        *(float4*)(t2 + (long)n * 65536 + p0 + q * 4) = v;
    }
}

// ---------------------------------------------------------------- OXO: h += t2*W^T + b (h split)
__global__ __launch_bounds__(256, 2)
void oxo_kernel(const unsigned* __restrict__ Tx, const unsigned* __restrict__ Bx,
                const float* __restrict__ ob, unsigned* __restrict__ h) {
    __shared__ float T[128 * 128];
    int tid = threadIdx.x;
    int w = tid >> 6, l = tid & 63;
    int lr = l & 15, lg = l >> 4;
    int m0 = blockIdx.x * 128;
    int n0 = w * 32;
    f32x4 acc[8][2] = {};
    for (int k0 = 0; k0 < 128; k0 += 32) {
        bf16x8 bh[2], bl[2];
#pragma unroll
        for (int ns = 0; ns < 2; ns++) {
            const unsigned* bp = Bx + (n0 + ns * 16 + lr) * 128 + k0 + lg * 8;
            i32x4 d0 = *(const i32x4*)bp;
            i32x4 d1 = *(const i32x4*)(bp + 4);
            unpack2(d0, d1, bh[ns], bl[ns]);
        }
#pragma unroll
        for (int ms = 0; ms < 8; ms++) {
            const unsigned* ap = Tx + (long)(k0 + lg * 8) * 65536 + m0 + ms * 16 + lr;
            int d[8];
#pragma unroll
            for (int j = 0; j < 8; j++) d[j] = (int)ap[(long)j * 65536];
            bf16x8 ah, al; unpack8(d, ah, al);
#pragma unroll
            for (int ns = 0; ns < 2; ns++) {
                acc[ms][ns] = __builtin_amdgcn_mfma_f32_16x16x32_bf16(ah, bh[ns], acc[ms][ns], 0, 0, 0);
                acc[ms][ns] = __builtin_amdgcn_mfma_f32_16x16x32_bf16(ah, bl[ns], acc[ms][ns], 0, 0, 0);
                acc[ms][ns] = __builtin_amdgcn_mfma_f32_16x16x32_bf16(al, bh[ns], acc[ms][ns], 0, 0, 0);
            }
        }
    }
#pragma unroll
    for (int ns = 0; ns < 2; ns++) {
        int n = n0 + ns * 16 + lr;
#pragma unroll
        for (int ms = 0; ms < 8; ms++) {
            int blk = ((ms * 4 + lg) + n) & 31;
#pragma unroll
            for (int r = 0; r < 4; r++)
                T[n * 128 + blk * 4 + r] = acc[ms][ns][r];
        }
    }
    __syncthreads();
#pragma unroll
    for (int i = 0; i < 16; i++) {
        int flat = i * 256 + tid;
        int n = flat >> 5, q = flat & 31;
        const float4* src = (const float4*)&T[n * 128 + (((q + n) & 31) * 4)];
        float4 v = *src;
        float bias = ob[n];
        unsigned* hp = h + (long)n * 65536 + m0 + q * 4;
        uint4 hv = *(uint4*)hp;
        uint4 o;
        o.x = splitf(upk(hv.x) + v.x + bias);
        o.y = splitf(upk(hv.y) + v.y + bias);
        o.z = splitf(upk(hv.z) + v.z + bias);
        o.w = splitf(upk(hv.w) + v.w + bias);
        *(uint4*)hp = o;
    }
}

// ---------------------------------------------------------------- row forward rfft (tiled freq, 64-ch half)
// freq layout: [img64][kt17][y256][kxl8] float2
__global__ void fft_row_fwd(const float* __restrict__ in, float2* __restrict__ freq, int c0) {
    __shared__ float2 A[4][256];
    __shared__ float2 B[4][256];
    __shared__ float2 TW[128];
    int tid = threadIdx.x;
    int img = blockIdx.x >> 6, rgrp = blockIdx.x & 63;
    if (tid < 128) {
        float sn, cs; __sincosf((PI2 / 256.f) * (float)tid, &sn, &cs);
        TW[tid] = make_float2(cs, sn);
    }
    {
        int r = tid >> 6, l = tid & 63;
        const float4* src = (const float4*)(in + ((long)(c0 + img) * 256 + rgrp * 4 + r) * 256);
        float4 v = src[l];
        A[r][l * 4 + 0] = make_float2(v.x, 0.f);
        A[r][l * 4 + 1] = make_float2(v.y, 0.f);
        A[r][l * 4 + 2] = make_float2(v.z, 0.f);
        A[r][l * 4 + 3] = make_float2(v.w, 0.f);
    }
    __syncthreads();
    float2 (*s)[256] = A; float2 (*d)[256] = B;
    for (int m = 1; m < 256; m <<= 1) {
#pragma unroll
        for (int q = 0; q < 2; q++) {
            int bf = tid + q * 256;
            int r = bf >> 7, i = bf & 127;
            int jm = i & ~(m - 1);
            float2 c0v = s[r][i], c1 = s[r][i + 128];
            float2 t = TW[jm];
            float2 df = make_float2(c0v.x - c1.x, c0v.y - c1.y);
            d[r][i + jm]     = make_float2(c0v.x + c1.x, c0v.y + c1.y);
            d[r][i + jm + m] = make_float2(t.x * df.x + t.y * df.y, t.x * df.y - t.y * df.x);
        }
        __syncthreads();
        float2 (*tmp)[256] = s; s = d; d = tmp;
    }
    long ib = (long)img * 34816;
    for (int q = tid; q < 4 * 129; q += 256) {
        int r = q / 129; int k = q - r * 129;
        freq[ib + (k >> 3) * 2048 + (rgrp * 4 + r) * 8 + (k & 7)] = s[r][k];
    }
}

// ---------------------------------------------------------------- column FFT + filter + inverse (tiled freq)
__global__ void fft_col(float2* __restrict__ freq, const float* __restrict__ mags,
                        const float* __restrict__ phases, int c0) {
    __shared__ float2 A[8][256];
    __shared__ float2 B[8][256];
    __shared__ float2 TW[128];
    int tid = threadIdx.x;
    int img = blockIdx.x / 17;
    int kt  = blockIdx.x % 17;
    int kx0 = kt * 8;
    float2* base = freq + (long)img * 34816 + kt * 2048;
    if (tid < 128) {
        float sn, cs; __sincosf((PI2 / 256.f) * (float)tid, &sn, &cs);
        TW[tid] = make_float2(cs, sn);
    }
#pragma unroll
    for (int q = 0; q < 8; q++) {
        int e = tid + q * 256;
        A[e & 7][e >> 3] = base[e];       // fully contiguous 16 KB
    }
    __syncthreads();
    float2 (*s)[256] = A; float2 (*d)[256] = B;
    for (int m = 1; m < 256; m <<= 1) {           // forward
#pragma unroll
        for (int q = 0; q < 4; q++) {
            int bf = tid + q * 256;
            int cl = bf >> 7, i = bf & 127;
            int jm = i & ~(m - 1);
            float2 c0v = s[cl][i], c1 = s[cl][i + 128];
            float2 t = TW[jm];
            float2 df = make_float2(c0v.x - c1.x, c0v.y - c1.y);
            d[cl][i + jm]     = make_float2(c0v.x + c1.x, c0v.y + c1.y);
            d[cl][i + jm + m] = make_float2(t.x * df.x + t.y * df.y, t.x * df.y - t.y * df.x);
        }
        __syncthreads();
        float2 (*tmp)[256] = s; s = d; d = tmp;
    }
#pragma unroll
    for (int q = 0; q < 8; q++) {
        int e = tid + q * 256;
        int cl = e & 7, ky = e >> 3;
        int kx = kx0 + cl;
        float2 v = s[cl][ky];
        float2 r = make_float2(0.f, 0.f);
        if (kx < 129) {
            int ry = ky < 128 ? ky : ky - 256;
            if (kx * kx + ry * ry <= 16384) {
                long fi = ((long)(c0 + img) * 256 + ky) * 129 + kx;
                float mg = mags[fi], ph = phases[fi];
                float sg = 1.0f / (1.0f + __expf(-mg));
                float sn, cs; __sincosf(ph, &sn, &cs);
                float fr = sg * cs, fim = sg * sn;
                r = make_float2(v.x * fr - v.y * fim, v.x * fim + v.y * fr);
            }
        }
        s[cl][ky] = r;
    }
    __syncthreads();
    for (int m = 1; m < 256; m <<= 1) {           // inverse
#pragma unroll
        for (int q = 0; q < 4; q++) {
            int bf = tid + q * 256;
            int cl = bf >> 7, i = bf & 127;
            int jm = i & ~(m - 1);
            float2 c0v = s[cl][i], c1 = s[cl][i + 128];
            float2 t = TW[jm];
            float2 df = make_float2(c0v.x - c1.x, c0v.y - c1.y);
            d[cl][i + jm]     = make_float2(c0v.x + c1.x, c0v.y + c1.y);
            d[cl][i + jm + m] = make_float2(t.x * df.x - t.y * df.y, t.x * df.y + t.y * df.x);
        }
        __syncthreads();
        float2 (*tmp)[256] = s; s = d; d = tmp;
    }
#pragma unroll
    for (int q = 0; q < 8; q++) {
        int e = tid + q * 256;
        base[e] = s[e & 7][e >> 3];
    }
}

// ---------------------------------------------------------------- row inverse rfft (tiled freq, SPLIT out)
__global__ void fft_row_inv(const float2* __restrict__ freq, unsigned* __restrict__ out, int c0) {
    __shared__ float2 A[4][256];
    __shared__ float2 B[4][256];
    __shared__ float2 TW[128];
    int tid = threadIdx.x;
    int img = blockIdx.x >> 6, rgrp = blockIdx.x & 63;
    if (tid < 128) {
        float sn, cs; __sincosf((PI2 / 256.f) * (float)tid, &sn, &cs);
        TW[tid] = make_float2(cs, sn);
    }
    long ib = (long)img * 34816;
#pragma unroll
    for (int q = 0; q < 4; q++) {
        int e = tid + q * 256;
        int r = e >> 8, xx = e & 255;
        int k = (xx <= 128) ? xx : 256 - xx;
        float2 v = freq[ib + (k >> 3) * 2048 + (rgrp * 4 + r) * 8 + (k & 7)];
        if (xx > 128) v.y = -v.y;
        A[r][xx] = v;
    }
    __syncthreads();
    float2 (*s)[256] = A; float2 (*d)[256] = B;
    for (int m = 1; m < 256; m <<= 1) {
#pragma unroll
        for (int q = 0; q < 2; q++) {
            int bf = tid + q * 256;
            int r = bf >> 7, i = bf & 127;
            int jm = i & ~(m - 1);
            float2 c0v = s[r][i], c1 = s[r][i + 128];
            float2 t = TW[jm];
            float2 df = make_float2(c0v.x - c1.x, c0v.y - c1.y);
            d[r][i + jm]     = make_float2(c0v.x + c1.x, c0v.y + c1.y);
            d[r][i + jm + m] = make_float2(t.x * df.x - t.y * df.y, t.x * df.y + t.y * df.x);
        }
        __syncthreads();
        float2 (*tmp)[256] = s; s = d; d = tmp;
    }
    {
        int r = tid >> 6, l = tid & 63;
        const float sc = 1.0f / 65536.0f;
        uint4 o;
        o.x = splitf(s[r][l * 4 + 0].x * sc);
        o.y = splitf(s[r][l * 4 + 1].x * sc);
        o.z = splitf(s[r][l * 4 + 2].x * sc);
        o.w = splitf(s[r][l * 4 + 3].x * sc);
        *(uint4*)(out + ((long)(c0 + img) * 256 + rgrp * 4 + r) * 256 + l * 4) = o;
    }
}

// ---------------------------------------------------------------- decoder (h split)
__global__ void dec_kernel(const unsigned* __restrict__ h, const float* __restrict__ w,
                           const float* __restrict__ b, float* __restrict__ out) {
    int t = blockIdx.x * 256 + threadIdx.x;
    int bb = t >> 16, p = t & 65535;
    const unsigned* hb = h + (long)bb * 8388608 + p;
    float a0 = b[0], a1 = b[1];
    float a0b = 0.f, a1b = 0.f;
#pragma unroll 4
    for (int c = 0; c < 128; c += 2) {
        float h0 = upk(hb[(long)c * 65536]);
        float h1 = upk(hb[(long)(c + 1) * 65536]);
        a0  += w[c] * h0;        a1  += w[128 + c] * h0;
        a0b += w[c + 1] * h1;    a1b += w[128 + c + 1] * h1;
    }
    out[((long)bb * 2 + 0) * 65536 + p] = (a0 + a0b) * 0.125f;
    out[((long)bb * 2 + 1) * 65536 + p] = (a1 + a1b) * 0.125f;
}

// ---------------------------------------------------------------- launch
extern "C" void kernel_launch(void* const* d_in, const int* in_sizes, int n_in,
                              void* d_out, int out_size, void* d_ws, size_t ws_size,
                              hipStream_t stream) {
    const float* x        = (const float*)d_in[0];
    const float* enc_w    = (const float*)d_in[1];
    const float* enc_b    = (const float*)d_in[2];
    const float* pos_emb  = (const float*)d_in[3];
    const float* mlp_w1   = (const float*)d_in[4];
    const float* mlp_b1   = (const float*)d_in[5];
    const float* mlp_w2   = (const float*)d_in[6];
    const float* mlp_b2   = (const float*)d_in[7];
    const float* spec_mag = (const float*)d_in[8];
    const float* spec_ph  = (const float*)d_in[9];
    const float* oxo_w    = (const float*)d_in[10];
    const float* oxo_b    = (const float*)d_in[11];
    const float* dec_w    = (const float*)d_in[12];
    const float* dec_b    = (const float*)d_in[13];
    float* outp = (float*)d_out;

    // ws layout (dwords):
    //  h (split)      33,554,432
    //  t2 / TxO        8,388,608
    //  freq (64ch)     4,456,448   ([img64][kt17][y256][kx8] float2)
    //  Wx1/Wx2/Wox       147,456
    //  total          46,546,944 dw = 186,187,776 B
    const size_t WS_NEEDED = 186187776ULL;
    if (ws_size < WS_NEEDED) {
        sentinel_kernel<<<(out_size + 255) / 256, 256, 0, stream>>>(outp, out_size);
        return;
    }

    unsigned* u    = (unsigned*)d_ws;
    unsigned* h    = u;
    float*    t2   = (float*)(u + 33554432);
    unsigned* TxO  = (unsigned*)t2;
    float2*   freq = (float2*)(u + 41943040);
    unsigned* Wx1  = u + 46399488;
    unsigned* Wx2  = Wx1 + 65536;
    unsigned* Wox  = Wx2 + 65536;

    enc_kernel<<<32768, 256, 0, stream>>>(x, enc_w, enc_b, pos_emb, h);

    for (int l = 0; l < 4; l++) {
        split_kernel<<<64, 256, 0, stream>>>(mlp_w1 + (long)l * 65536, Wx1);
        split_kernel<<<64, 256, 0, stream>>>(mlp_w2 + (long)l * 65536, Wx2);
        split_kernel<<<16, 256, 0, stream>>>(oxo_w + (long)l * 16384, Wox);
        const float* b1l = mlp_b1 + l * 512;
        const float* b2l = mlp_b2 + l * 128;
        const float* mgl = spec_mag + (long)l * 4227072;
        const float* phl = spec_ph  + (long)l * 4227072;
        const float* obl = oxo_b + l * 128;
        for (int b = 0; b < 4; b++) {
            unsigned* hb = h + (long)b * 8388608;
            mlp_fused<<<1024, 256, 0, stream>>>(hb, Wx1, b1l, Wx2, b2l, t2);
            for (int c0 = 0; c0 < 128; c0 += 64) {
                fft_row_fwd<<<4096, 256, 0, stream>>>(t2, freq, c0);
                fft_col<<<64 * 17, 256, 0, stream>>>(freq, mgl, phl, c0);
                fft_row_inv<<<4096, 256, 0, stream>>>(freq, TxO, c0);
            }
            oxo_kernel<<<512, 256, 0, stream>>>(TxO, Wox, obl, hb);
        }
    }

    dec_kernel<<<1024, 256, 0, stream>>>(h, dec_w, dec_b, outp);
}